// Round 1
// baseline (728.091 us; speedup 1.0000x reference)
//
#include <hip/hip_runtime.h>
#include <hip/hip_bf16.h>
#include <cstdint>

#define AS1 __attribute__((address_space(1)))
#define AS3 __attribute__((address_space(3)))

typedef __bf16 bf16x8 __attribute__((ext_vector_type(8)));
typedef float  f32x4  __attribute__((ext_vector_type(4)));

__device__ __forceinline__ void gld_lds16(const void* g, void* l) {
    __builtin_amdgcn_global_load_lds((const AS1 void*)g, (AS3 void*)l, 16, 0, 0);
}

// ---------------- Kernel 1: rotated 3x3 kernels (exact fp32 replica) ----------------
__global__ void k_rot(const float* __restrict__ base, float* __restrict__ w1) {
    int m = threadIdx.x;            // 0..127 = g*16+o
    int g = m >> 4, o = m & 15;
    float th = 6.28318530717958647692f * (float)g / 8.0f;
    float c = cosf(th), s = sinf(th);
    for (int i = 0; i < 3; ++i) {           // row (y)
        float ys = (2.0f * i + 1.0f) / 3.0f - 1.0f;
        for (int j = 0; j < 3; ++j) {       // col (x)
            float xs = (2.0f * j + 1.0f) / 3.0f - 1.0f;
            float gx = c * xs - s * ys;
            float gy = s * xs + c * ys;
            float px = ((gx + 1.0f) * 3.0f - 1.0f) * 0.5f;
            float py = ((gy + 1.0f) * 3.0f - 1.0f) * 0.5f;
            float x0 = floorf(px), y0 = floorf(py);
            float wx = px - x0, wy = py - y0;
            int x0i = (int)x0, y0i = (int)y0;
            auto gat = [&](int yi, int xi) -> float {
                bool v = (yi >= 0) && (yi < 3) && (xi >= 0) && (xi < 3);
                int yc = min(max(yi, 0), 2), xc = min(max(xi, 0), 2);
                return v ? base[o * 9 + yc * 3 + xc] : 0.0f;
            };
            float val = gat(y0i, x0i)       * (1.0f - wx) * (1.0f - wy)
                      + gat(y0i, x0i + 1)   * wx          * (1.0f - wy)
                      + gat(y0i + 1, x0i)   * (1.0f - wx) * wy
                      + gat(y0i + 1, x0i + 1) * wx        * wy;
            w1[m * 9 + i * 3 + j] = val;
        }
    }
}

// ---------------- Kernel 2: build bf16 GEMM A matrix [256][1152] ----------------
// A[r][k], r = g*32 + o2 (natural Wbig row), k = (ky*3+kx)*128 + c, c = c2*8+hh
// value = w2[o2, c2, (g-hh)%8, ky, kx]
__global__ void k_build_a(const float* __restrict__ w2, __hip_bfloat16* __restrict__ A) {
    int i = blockIdx.x * 256 + threadIdx.x;   // < 256*1152, grid exact
    int r = i / 1152, k = i - r * 1152;
    int g = r >> 5, o2 = r & 31;
    int kk = k >> 7, cch = k & 127;
    int ky = kk / 3, kx = kk - ky * 3;
    int c2 = cch >> 3, hh = cch & 7;
    int gi = (g - hh) & 7;
    A[i] = __float2bfloat16(w2[((o2 * 16 + c2) * 8 + gi) * 9 + ky * 3 + kx]);
}

// ---------------- Kernel 3: conv1 + relu -> channel-last padded bf16 h ----------------
// hl layout: [b][yy 0..29][xx 0..29][c 0..127], borders = 0
__global__ void k_conv1(const float* __restrict__ x, const float* __restrict__ w1,
                        __hip_bfloat16* __restrict__ hl) {
    int c  = threadIdx.x & 127;
    int pi = blockIdx.x * 2 + (threadIdx.x >> 7);   // pixel index < 512*30*30
    int xx = pi % 30; int t = pi / 30; int yy = t % 30; int b = t / 30;
    float v = 0.0f;
    if (xx >= 1 && xx <= 28 && yy >= 1 && yy <= 28) {
        int y = yy - 1, xc = xx - 1;
        const float* xb = x + b * 784;
        const float* wc = w1 + c * 9;
        float acc = 0.0f;
#pragma unroll
        for (int dy = -1; dy <= 1; ++dy) {
            int sy = y + dy;
#pragma unroll
            for (int dx = -1; dx <= 1; ++dx) {
                int sx = xc + dx;
                float xv = (sy >= 0 && sy < 28 && sx >= 0 && sx < 28) ? xb[sy * 28 + sx] : 0.0f;
                acc += xv * wc[(dy + 1) * 3 + (dx + 1)];
            }
        }
        v = fmaxf(acc, 0.0f);
    }
    hl[(size_t)pi * 128 + c] = __float2bfloat16(v);
}

// ---------------- Kernel 4: conv2 implicit GEMM + relu + 8-channel mean -> p ----------------
// Block: 256 thr (4 waves 2x2), tile M=128 x N=128, BK=64, 18 stages.
// N cols: n = (b, y0+dy, x in 0..31), x>=28 = padded garbage (discarded).
__global__ __launch_bounds__(256) void k_conv2(const __hip_bfloat16* __restrict__ A,
                                               const __hip_bfloat16* __restrict__ hl,
                                               float* __restrict__ p) {
    __shared__ __align__(16) char smem[32768];   // As [128][64] bf16 | Bs [128][64] bf16

    const int tid  = threadIdx.x;
    const int lane = tid & 63;
    const int w    = tid >> 6;
    const int wr   = w >> 1, wc = w & 1;
    const int quad = lane >> 4;

    const int mt = blockIdx.x & 1;
    const int nt = blockIdx.x >> 1;      // < 3584
    const int b  = nt / 7;
    const int y0 = (nt - b * 7) * 4;
    const int r0 = mt << 7;

    // staging constants (4 global_load_lds instrs per wave per tile)
    uint32_t aG[4], bG[4], ldsOff[4];
#pragma unroll
    for (int q = 0; q < 4; ++q) {
        int ch = w * 4 + q;
        int rl = ch * 8 + (lane >> 3);            // tile-local row / col 0..127
        int ca = (lane & 7) ^ (rl & 7);           // xor-swizzled chunk to fetch
        aG[q] = (uint32_t)((r0 + rl) * 2304 + ca * 16);
        bG[q] = (uint32_t)(((b * 30 + y0 + (rl >> 5)) * 30 + (rl & 31)) * 256 + ca * 16);
        ldsOff[q] = (uint32_t)(ch * 1024);
    }

    // fragment-read constants
    uint32_t aro[4], bro[4]; int asw[4], bsw[4];
#pragma unroll
    for (int i = 0; i < 4; ++i) {
        int rl = 64 * wr + 16 * i + (lane & 15);
        aro[i] = (uint32_t)(rl * 128); asw[i] = rl & 7;
        int nl = 64 * wc + 16 * i + (lane & 15);
        bro[i] = (uint32_t)(16384 + nl * 128); bsw[i] = nl & 7;
    }

    f32x4 acc[4][4];
#pragma unroll
    for (int i = 0; i < 4; ++i)
#pragma unroll
        for (int j = 0; j < 4; ++j) acc[i][j] = (f32x4)(0.0f);

    const char* Ab = (const char*)A;
    const char* Hb = (const char*)hl;

    for (int s = 0; s < 18; ++s) {
        int kk = s >> 1, half = s & 1;
        int ky = kk / 3, kx = kk - ky * 3;
        int aoff = kk * 256 + half * 128;                    // bytes into A row
        int boff = (ky * 30 + kx) * 256 + half * 128;        // bytes into hl

        __syncthreads();
#pragma unroll
        for (int q = 0; q < 4; ++q) {
            gld_lds16(Ab + aG[q] + aoff, smem + ldsOff[q]);
            gld_lds16(Hb + bG[q] + boff, smem + 16384 + ldsOff[q]);
        }
        __syncthreads();

#pragma unroll
        for (int ks = 0; ks < 2; ++ks) {
            int cb = ks * 4 + quad;
            bf16x8 af[4], bf[4];
#pragma unroll
            for (int i = 0; i < 4; ++i) {
                af[i] = *(const bf16x8*)(smem + aro[i] + ((cb ^ asw[i]) * 16));
                bf[i] = *(const bf16x8*)(smem + bro[i] + ((cb ^ bsw[i]) * 16));
            }
#pragma unroll
            for (int i = 0; i < 4; ++i)
#pragma unroll
                for (int j = 0; j < 4; ++j)
                    acc[i][j] = __builtin_amdgcn_mfma_f32_16x16x32_bf16(af[i], bf[j], acc[i][j], 0, 0, 0);
        }
    }

    // epilogue: relu, mean over 8 consecutive rows (= reference's reshape(.,32,8,.).mean)
#pragma unroll
    for (int i = 0; i < 4; ++i) {
        int grp = (r0 + 64 * wr + 16 * i) >> 3;   // pool-group index 'a' for quads 0/1
#pragma unroll
        for (int j = 0; j < 4; ++j) {
            f32x4 v = acc[i][j];
            float sv = fmaxf(v[0], 0.0f) + fmaxf(v[1], 0.0f) + fmaxf(v[2], 0.0f) + fmaxf(v[3], 0.0f);
            sv += __shfl_xor(sv, 16, 64);         // rows 0-3 + rows 4-7 (or 8-11 + 12-15)
            int nl = 64 * wc + 16 * j + (lane & 15);
            int xcol = nl & 31;
            if (((quad & 1) == 0) && xcol < 28) {
                int a = grp + (quad >> 1);
                int y = y0 + (nl >> 5);
                p[((b * 32 + a) * 28 + y) * 28 + xcol] = sv * 0.125f;
            }
        }
    }
}

// ---------------- Kernel 5: FC ----------------
__global__ void k_fc(const float* __restrict__ p, const float* __restrict__ fw,
                     const float* __restrict__ fb, float* __restrict__ out) {
    int b = blockIdx.x, tid = threadIdx.x;
    const float4* p4 = (const float4*)(p + (size_t)b * 25088);
    const float4* w4 = (const float4*)fw;
    float acc[10] = {};
    for (int i = tid; i < 6272; i += 256) {
        float4 v = p4[i];
#pragma unroll
        for (int c = 0; c < 10; ++c) {
            float4 u = w4[c * 6272 + i];
            acc[c] += v.x * u.x + v.y * u.y + v.z * u.z + v.w * u.w;
        }
    }
    __shared__ float red[10][4];
    int lane = tid & 63, wv = tid >> 6;
#pragma unroll
    for (int c = 0; c < 10; ++c) {
        float s = acc[c];
#pragma unroll
        for (int o = 32; o > 0; o >>= 1) s += __shfl_down(s, o, 64);
        if (lane == 0) red[c][wv] = s;
    }
    __syncthreads();
    if (tid < 10)
        out[b * 10 + tid] = red[tid][0] + red[tid][1] + red[tid][2] + red[tid][3] + fb[tid];
}

// ---------------- launch ----------------
extern "C" void kernel_launch(void* const* d_in, const int* in_sizes, int n_in,
                              void* d_out, int out_size, void* d_ws, size_t ws_size,
                              hipStream_t stream) {
    const float* x  = (const float*)d_in[0];
    const float* bw = (const float*)d_in[1];
    const float* w2 = (const float*)d_in[2];
    const float* fw = (const float*)d_in[3];
    const float* fb = (const float*)d_in[4];
    float* out = (float*)d_out;
    char* ws = (char*)d_ws;

    // ws layout (bytes): w1 fp32 4608 | A bf16 589824 | hl bf16 117968896 (incl 2MB-ish slack for x-spill) | p fp32 51380224
    float*          w1   = (float*)(ws);
    __hip_bfloat16* Amat = (__hip_bfloat16*)(ws + 4608);
    __hip_bfloat16* hl   = (__hip_bfloat16*)(ws + 594432);
    float*          p    = (float*)(ws + 118563328);

    k_rot    <<<1,      128, 0, stream>>>(bw, w1);
    k_build_a<<<1152,   256, 0, stream>>>(w2, Amat);
    k_conv1  <<<230400, 256, 0, stream>>>(x, w1, hl);
    k_conv2  <<<7168,   256, 0, stream>>>(Amat, hl, p);
    k_fc     <<<512,    256, 0, stream>>>(p, fw, fb, out);
}

// Round 2
// 443.505 us; speedup vs baseline: 1.6417x; 1.6417x over previous
//
#include <hip/hip_runtime.h>
#include <hip/hip_bf16.h>
#include <cstdint>

#define AS1 __attribute__((address_space(1)))
#define AS3 __attribute__((address_space(3)))

typedef __bf16 bf16x8 __attribute__((ext_vector_type(8)));
typedef float  f32x4  __attribute__((ext_vector_type(4)));

__device__ __forceinline__ void gld_lds16(const void* g, void* l) {
    __builtin_amdgcn_global_load_lds((const AS1 void*)g, (AS3 void*)l, 16, 0, 0);
}

// ---------------- Kernel 1: rotated 3x3 kernels (exact fp32 replica) ----------------
__global__ void k_rot(const float* __restrict__ base, float* __restrict__ w1) {
    int m = threadIdx.x;            // 0..127 = g*16+o
    int g = m >> 4, o = m & 15;
    float th = 6.28318530717958647692f * (float)g / 8.0f;
    float c = cosf(th), s = sinf(th);
    for (int i = 0; i < 3; ++i) {           // row (y)
        float ys = (2.0f * i + 1.0f) / 3.0f - 1.0f;
        for (int j = 0; j < 3; ++j) {       // col (x)
            float xs = (2.0f * j + 1.0f) / 3.0f - 1.0f;
            float gx = c * xs - s * ys;
            float gy = s * xs + c * ys;
            float px = ((gx + 1.0f) * 3.0f - 1.0f) * 0.5f;
            float py = ((gy + 1.0f) * 3.0f - 1.0f) * 0.5f;
            float x0 = floorf(px), y0 = floorf(py);
            float wx = px - x0, wy = py - y0;
            int x0i = (int)x0, y0i = (int)y0;
            auto gat = [&](int yi, int xi) -> float {
                bool v = (yi >= 0) && (yi < 3) && (xi >= 0) && (xi < 3);
                int yc = min(max(yi, 0), 2), xc = min(max(xi, 0), 2);
                return v ? base[o * 9 + yc * 3 + xc] : 0.0f;
            };
            float val = gat(y0i, x0i)       * (1.0f - wx) * (1.0f - wy)
                      + gat(y0i, x0i + 1)   * wx          * (1.0f - wy)
                      + gat(y0i + 1, x0i)   * (1.0f - wx) * wy
                      + gat(y0i + 1, x0i + 1) * wx        * wy;
            w1[m * 9 + i * 3 + j] = val;
        }
    }
}

// ---------------- Kernel 2: build bf16 GEMM A matrix [256][1152] ----------------
__global__ void k_build_a(const float* __restrict__ w2, __hip_bfloat16* __restrict__ A) {
    int i = blockIdx.x * 256 + threadIdx.x;   // < 256*1152, grid exact
    int r = i / 1152, k = i - r * 1152;
    int g = r >> 5, o2 = r & 31;
    int kk = k >> 7, cch = k & 127;
    int ky = kk / 3, kx = kk - ky * 3;
    int c2 = cch >> 3, hh = cch & 7;
    int gi = (g - hh) & 7;
    A[i] = __float2bfloat16(w2[((o2 * 16 + c2) * 8 + gi) * 9 + ky * 3 + kx]);
}

// ---------------- Kernel 3: conv1 + relu -> channel-last padded bf16 h ----------------
// hl layout: [b][yy 0..29][xx 0..29][c 0..127], borders = 0
// Block 256 thr: tid&15 = channel-group (8 ch), tid>>4 = pixel slot; 4 pixels/thread.
// Each thread: 72 weight regs, 9 x-loads/pixel (L1 broadcast), one 16B store/pixel.
__global__ __launch_bounds__(256) void k_conv1(const float* __restrict__ x,
                                               const float* __restrict__ w1,
                                               __hip_bfloat16* __restrict__ hl) {
    __shared__ float w1s[1152];
    int tid = threadIdx.x;
    for (int i = tid; i < 1152; i += 256) w1s[i] = w1[i];
    __syncthreads();

    const int c0 = (tid & 15) * 8;
    float wreg[8][9];
#pragma unroll
    for (int cc = 0; cc < 8; ++cc)
#pragma unroll
        for (int k = 0; k < 9; ++k) wreg[cc][k] = w1s[(c0 + cc) * 9 + k];

    const int ps = tid >> 4;              // pixel slot 0..15
    const int base = blockIdx.x * 64;     // 64 pixels per block; grid 7200 exact

#pragma unroll
    for (int j = 0; j < 4; ++j) {
        int pi = base + j * 16 + ps;      // < 512*900
        int xx = pi % 30; int t = pi / 30; int yy = t % 30; int b = t / 30;
        float acc[8] = {0.f,0.f,0.f,0.f,0.f,0.f,0.f,0.f};
        if (xx >= 1 && xx <= 28 && yy >= 1 && yy <= 28) {
            const float* xb = x + b * 784;
            int y = yy - 1, xc = xx - 1;
#pragma unroll
            for (int dy = -1; dy <= 1; ++dy) {
                int sy = y + dy;
#pragma unroll
                for (int dx = -1; dx <= 1; ++dx) {
                    int sx = xc + dx;
                    float xv = (sy >= 0 && sy < 28 && sx >= 0 && sx < 28) ? xb[sy * 28 + sx] : 0.0f;
                    int k = (dy + 1) * 3 + (dx + 1);
#pragma unroll
                    for (int cc = 0; cc < 8; ++cc) acc[cc] += xv * wreg[cc][k];
                }
            }
        }
        union { __hip_bfloat16 h[8]; float4 f4; } u;
#pragma unroll
        for (int cc = 0; cc < 8; ++cc) u.h[cc] = __float2bfloat16(fmaxf(acc[cc], 0.0f));
        *(float4*)(hl + (size_t)pi * 128 + c0) = u.f4;
    }
}

// ---------------- Kernel 4: conv2 implicit GEMM + relu + 8-channel mean -> p ----------------
__global__ __launch_bounds__(256) void k_conv2(const __hip_bfloat16* __restrict__ A,
                                               const __hip_bfloat16* __restrict__ hl,
                                               float* __restrict__ p) {
    __shared__ __align__(16) char smem[32768];   // As [128][64] bf16 | Bs [128][64] bf16

    const int tid  = threadIdx.x;
    const int lane = tid & 63;
    const int w    = tid >> 6;
    const int wr   = w >> 1, wc = w & 1;
    const int quad = lane >> 4;

    const int mt = blockIdx.x & 1;
    const int nt = blockIdx.x >> 1;      // < 3584
    const int b  = nt / 7;
    const int y0 = (nt - b * 7) * 4;
    const int r0 = mt << 7;

    uint32_t aG[4], bG[4], ldsOff[4];
#pragma unroll
    for (int q = 0; q < 4; ++q) {
        int ch = w * 4 + q;
        int rl = ch * 8 + (lane >> 3);
        int ca = (lane & 7) ^ (rl & 7);
        aG[q] = (uint32_t)((r0 + rl) * 2304 + ca * 16);
        bG[q] = (uint32_t)(((b * 30 + y0 + (rl >> 5)) * 30 + (rl & 31)) * 256 + ca * 16);
        ldsOff[q] = (uint32_t)(ch * 1024);
    }

    uint32_t aro[4], bro[4]; int asw[4], bsw[4];
#pragma unroll
    for (int i = 0; i < 4; ++i) {
        int rl = 64 * wr + 16 * i + (lane & 15);
        aro[i] = (uint32_t)(rl * 128); asw[i] = rl & 7;
        int nl = 64 * wc + 16 * i + (lane & 15);
        bro[i] = (uint32_t)(16384 + nl * 128); bsw[i] = nl & 7;
    }

    f32x4 acc[4][4];
#pragma unroll
    for (int i = 0; i < 4; ++i)
#pragma unroll
        for (int j = 0; j < 4; ++j) acc[i][j] = (f32x4)(0.0f);

    const char* Ab = (const char*)A;
    const char* Hb = (const char*)hl;

    for (int s = 0; s < 18; ++s) {
        int kk = s >> 1, half = s & 1;
        int ky = kk / 3, kx = kk - ky * 3;
        int aoff = kk * 256 + half * 128;
        int boff = (ky * 30 + kx) * 256 + half * 128;

        __syncthreads();
#pragma unroll
        for (int q = 0; q < 4; ++q) {
            gld_lds16(Ab + aG[q] + aoff, smem + ldsOff[q]);
            gld_lds16(Hb + bG[q] + boff, smem + 16384 + ldsOff[q]);
        }
        __syncthreads();

#pragma unroll
        for (int ks = 0; ks < 2; ++ks) {
            int cb = ks * 4 + quad;
            bf16x8 af[4], bf[4];
#pragma unroll
            for (int i = 0; i < 4; ++i) {
                af[i] = *(const bf16x8*)(smem + aro[i] + ((cb ^ asw[i]) * 16));
                bf[i] = *(const bf16x8*)(smem + bro[i] + ((cb ^ bsw[i]) * 16));
            }
#pragma unroll
            for (int i = 0; i < 4; ++i)
#pragma unroll
                for (int j = 0; j < 4; ++j)
                    acc[i][j] = __builtin_amdgcn_mfma_f32_16x16x32_bf16(af[i], bf[j], acc[i][j], 0, 0, 0);
        }
    }

#pragma unroll
    for (int i = 0; i < 4; ++i) {
        int grp = (r0 + 64 * wr + 16 * i) >> 3;
#pragma unroll
        for (int j = 0; j < 4; ++j) {
            f32x4 v = acc[i][j];
            float sv = fmaxf(v[0], 0.0f) + fmaxf(v[1], 0.0f) + fmaxf(v[2], 0.0f) + fmaxf(v[3], 0.0f);
            sv += __shfl_xor(sv, 16, 64);
            int nl = 64 * wc + 16 * j + (lane & 15);
            int xcol = nl & 31;
            if (((quad & 1) == 0) && xcol < 28) {
                int a = grp + (quad >> 1);
                int y = y0 + (nl >> 5);
                p[((b * 32 + a) * 28 + y) * 28 + xcol] = sv * 0.125f;
            }
        }
    }
}

// ---------------- Kernel 5: FC ----------------
__global__ void k_fc(const float* __restrict__ p, const float* __restrict__ fw,
                     const float* __restrict__ fb, float* __restrict__ out) {
    int b = blockIdx.x, tid = threadIdx.x;
    const float4* p4 = (const float4*)(p + (size_t)b * 25088);
    const float4* w4 = (const float4*)fw;
    float acc[10] = {};
    for (int i = tid; i < 6272; i += 256) {
        float4 v = p4[i];
#pragma unroll
        for (int c = 0; c < 10; ++c) {
            float4 u = w4[c * 6272 + i];
            acc[c] += v.x * u.x + v.y * u.y + v.z * u.z + v.w * u.w;
        }
    }
    __shared__ float red[10][4];
    int lane = tid & 63, wv = tid >> 6;
#pragma unroll
    for (int c = 0; c < 10; ++c) {
        float s = acc[c];
#pragma unroll
        for (int o = 32; o > 0; o >>= 1) s += __shfl_down(s, o, 64);
        if (lane == 0) red[c][wv] = s;
    }
    __syncthreads();
    if (tid < 10)
        out[b * 10 + tid] = red[tid][0] + red[tid][1] + red[tid][2] + red[tid][3] + fb[tid];
}

// ---------------- launch ----------------
extern "C" void kernel_launch(void* const* d_in, const int* in_sizes, int n_in,
                              void* d_out, int out_size, void* d_ws, size_t ws_size,
                              hipStream_t stream) {
    const float* x  = (const float*)d_in[0];
    const float* bw = (const float*)d_in[1];
    const float* w2 = (const float*)d_in[2];
    const float* fw = (const float*)d_in[3];
    const float* fb = (const float*)d_in[4];
    float* out = (float*)d_out;
    char* ws = (char*)d_ws;

    float*          w1   = (float*)(ws);
    __hip_bfloat16* Amat = (__hip_bfloat16*)(ws + 4608);
    __hip_bfloat16* hl   = (__hip_bfloat16*)(ws + 594432);
    float*          p    = (float*)(ws + 118563328);

    k_rot    <<<1,      128, 0, stream>>>(bw, w1);
    k_build_a<<<1152,   256, 0, stream>>>(w2, Amat);
    k_conv1  <<<7200,   256, 0, stream>>>(x, w1, hl);
    k_conv2  <<<7168,   256, 0, stream>>>(Amat, hl, p);
    k_fc     <<<512,    256, 0, stream>>>(p, fw, fb, out);
}

// Round 3
// 439.460 us; speedup vs baseline: 1.6568x; 1.0092x over previous
//
#include <hip/hip_runtime.h>
#include <hip/hip_bf16.h>
#include <cstdint>

#define AS1 __attribute__((address_space(1)))
#define AS3 __attribute__((address_space(3)))

typedef __bf16 bf16x8 __attribute__((ext_vector_type(8)));
typedef float  f32x4  __attribute__((ext_vector_type(4)));

__device__ __forceinline__ void gld_lds16(const void* g, void* l) {
    __builtin_amdgcn_global_load_lds((const AS1 void*)g, (AS3 void*)l, 16, 0, 0);
}

// ---------------- Kernel 1: build bf16 GEMM A matrix [256][1152] ----------------
// A[r][k], r = g*32 + o2, k = (ky*3+kx)*128 + c2*8 + hh; value = w2[o2, c2, (g-hh)%8, ky, kx]
__global__ void k_build_a(const float* __restrict__ w2, __hip_bfloat16* __restrict__ A) {
    int i = blockIdx.x * 256 + threadIdx.x;   // grid exact: 256*1152
    int r = i / 1152, k = i - r * 1152;
    int g = r >> 5, o2 = r & 31;
    int kk = k >> 7, cch = k & 127;
    int ky = kk / 3, kx = kk - ky * 3;
    int c2 = cch >> 3, hh = cch & 7;
    int gi = (g - hh) & 7;
    A[i] = __float2bfloat16(w2[((o2 * 16 + c2) * 8 + gi) * 9 + ky * 3 + kx]);
}

// ---------------- Kernel 2: conv1 + relu -> channel-last padded bf16 h ----------------
// Rotation of base weights computed in-block (fp32, exact replica of reference math).
// hl layout: [b][yy 0..29][xx 0..29][c 0..127], borders = 0.
__global__ __launch_bounds__(256) void k_conv1(const float* __restrict__ x,
                                               const float* __restrict__ base,
                                               __hip_bfloat16* __restrict__ hl) {
    __shared__ float w1s[1152];
    int tid = threadIdx.x;
    if (tid < 128) {
        int g = tid >> 4, o = tid & 15;
        float th = 6.28318530717958647692f * (float)g / 8.0f;
        float c = cosf(th), s = sinf(th);
        for (int i = 0; i < 3; ++i) {
            float ys = (2.0f * i + 1.0f) / 3.0f - 1.0f;
            for (int j = 0; j < 3; ++j) {
                float xs = (2.0f * j + 1.0f) / 3.0f - 1.0f;
                float gx = c * xs - s * ys;
                float gy = s * xs + c * ys;
                float px = ((gx + 1.0f) * 3.0f - 1.0f) * 0.5f;
                float py = ((gy + 1.0f) * 3.0f - 1.0f) * 0.5f;
                float x0 = floorf(px), y0 = floorf(py);
                float wx = px - x0, wy = py - y0;
                int x0i = (int)x0, y0i = (int)y0;
                auto gat = [&](int yi, int xi) -> float {
                    bool v = (yi >= 0) && (yi < 3) && (xi >= 0) && (xi < 3);
                    int yc = min(max(yi, 0), 2), xc = min(max(xi, 0), 2);
                    return v ? base[o * 9 + yc * 3 + xc] : 0.0f;
                };
                w1s[tid * 9 + i * 3 + j] =
                      gat(y0i, x0i)         * (1.0f - wx) * (1.0f - wy)
                    + gat(y0i, x0i + 1)     * wx          * (1.0f - wy)
                    + gat(y0i + 1, x0i)     * (1.0f - wx) * wy
                    + gat(y0i + 1, x0i + 1) * wx          * wy;
            }
        }
    }
    __syncthreads();

    const int c0 = (tid & 15) * 8;
    float wreg[8][9];
#pragma unroll
    for (int cc = 0; cc < 8; ++cc)
#pragma unroll
        for (int k = 0; k < 9; ++k) wreg[cc][k] = w1s[(c0 + cc) * 9 + k];

    const int ps = tid >> 4;              // pixel slot 0..15
    const int pbase = blockIdx.x * 64;    // grid 7200 exact -> 512*900 pixels

#pragma unroll
    for (int j = 0; j < 4; ++j) {
        int pi = pbase + j * 16 + ps;
        int xx = pi % 30; int t = pi / 30; int yy = t % 30; int b = t / 30;
        float acc[8] = {0.f,0.f,0.f,0.f,0.f,0.f,0.f,0.f};
        if (xx >= 1 && xx <= 28 && yy >= 1 && yy <= 28) {
            const float* xb = x + b * 784;
            int y = yy - 1, xc = xx - 1;
#pragma unroll
            for (int dy = -1; dy <= 1; ++dy) {
                int sy = y + dy;
#pragma unroll
                for (int dx = -1; dx <= 1; ++dx) {
                    int sx = xc + dx;
                    float xv = (sy >= 0 && sy < 28 && sx >= 0 && sx < 28) ? xb[sy * 28 + sx] : 0.0f;
                    int k = (dy + 1) * 3 + (dx + 1);
#pragma unroll
                    for (int cc = 0; cc < 8; ++cc) acc[cc] += xv * wreg[cc][k];
                }
            }
        }
        union { __hip_bfloat16 h[8]; float4 f4; } u;
#pragma unroll
        for (int cc = 0; cc < 8; ++cc) u.h[cc] = __float2bfloat16(fmaxf(acc[cc], 0.0f));
        *(float4*)(hl + (size_t)pi * 128 + c0) = u.f4;
    }
}

// ---------------- Kernel 3: conv2 implicit GEMM + relu + 8-channel mean -> p ----------------
// Dense-N packing: n = b*784 + y*28 + x (no padded columns). The padded-30 hl layout
// absorbs the (ky,kx) shifts: pixel addr = ((b*30 + y+ky)*30 + x+kx)*256 bytes.
__global__ __launch_bounds__(256) void k_conv2(const __hip_bfloat16* __restrict__ A,
                                               const __hip_bfloat16* __restrict__ hl,
                                               float* __restrict__ p) {
    __shared__ __align__(16) char smem[32768];   // As [128][64] bf16 | Bs [128][64] bf16

    const int tid  = threadIdx.x;
    const int lane = tid & 63;
    const int w    = tid >> 6;
    const int wr   = w >> 1, wc = w & 1;
    const int quad = lane >> 4;

    const int mt = blockIdx.x & 1;
    const int nt = blockIdx.x >> 1;      // < 3136
    const int n0 = nt << 7;
    const int r0 = mt << 7;

    // staging constants
    uint32_t aG[4], bG[4], ldsOff[4];
#pragma unroll
    for (int q = 0; q < 4; ++q) {
        int ch = w * 4 + q;
        int rl = ch * 8 + (lane >> 3);            // tile-local row / col 0..127
        int ca = (lane & 7) ^ (rl & 7);           // xor-swizzled chunk to fetch
        aG[q] = (uint32_t)((r0 + rl) * 2304 + ca * 16);
        int n  = n0 + rl;
        int b  = n / 784; int rr = n - b * 784;
        int y  = rr / 28; int xx = rr - y * 28;
        bG[q]  = (uint32_t)(((b * 30 + y) * 30 + xx) * 256 + ca * 16);
        ldsOff[q] = (uint32_t)(ch * 1024);
    }

    // fragment-read constants
    uint32_t aro[4], bro[4]; int asw[4], bsw[4];
#pragma unroll
    for (int i = 0; i < 4; ++i) {
        int rl = 64 * wr + 16 * i + (lane & 15);
        aro[i] = (uint32_t)(rl * 128); asw[i] = rl & 7;
        int nl = 64 * wc + 16 * i + (lane & 15);
        bro[i] = (uint32_t)(16384 + nl * 128); bsw[i] = nl & 7;
    }

    f32x4 acc[4][4];
#pragma unroll
    for (int i = 0; i < 4; ++i)
#pragma unroll
        for (int j = 0; j < 4; ++j) acc[i][j] = (f32x4)(0.0f);

    const char* Ab = (const char*)A;
    const char* Hb = (const char*)hl;

    for (int s = 0; s < 18; ++s) {
        int kk = s >> 1, half = s & 1;
        int ky = kk / 3, kx = kk - ky * 3;
        int aoff = kk * 256 + half * 128;                    // bytes into A row
        int boff = (ky * 30 + kx) * 256 + half * 128;        // bytes into hl

        __syncthreads();
#pragma unroll
        for (int q = 0; q < 4; ++q) {
            gld_lds16(Ab + aG[q] + aoff, smem + ldsOff[q]);
            gld_lds16(Hb + bG[q] + boff, smem + 16384 + ldsOff[q]);
        }
        __syncthreads();

#pragma unroll
        for (int ks = 0; ks < 2; ++ks) {
            int cb = ks * 4 + quad;
            bf16x8 af[4], bf[4];
#pragma unroll
            for (int i = 0; i < 4; ++i) {
                af[i] = *(const bf16x8*)(smem + aro[i] + ((cb ^ asw[i]) * 16));
                bf[i] = *(const bf16x8*)(smem + bro[i] + ((cb ^ bsw[i]) * 16));
            }
#pragma unroll
            for (int i = 0; i < 4; ++i)
#pragma unroll
                for (int j = 0; j < 4; ++j)
                    acc[i][j] = __builtin_amdgcn_mfma_f32_16x16x32_bf16(af[i], bf[j], acc[i][j], 0, 0, 0);
        }
    }

    // epilogue: relu, mean over 8 consecutive M-rows (pool groups), dense-n decode
#pragma unroll
    for (int i = 0; i < 4; ++i) {
        int grp = (r0 + 64 * wr + 16 * i) >> 3;   // pool-group base for quads 0/1
#pragma unroll
        for (int j = 0; j < 4; ++j) {
            f32x4 v = acc[i][j];
            float sv = fmaxf(v[0], 0.0f) + fmaxf(v[1], 0.0f) + fmaxf(v[2], 0.0f) + fmaxf(v[3], 0.0f);
            sv += __shfl_xor(sv, 16, 64);         // combine row halves of the 8-group
            if ((quad & 1) == 0) {
                int nl = 64 * wc + 16 * j + (lane & 15);
                int n  = n0 + nl;
                int b  = n / 784; int rr = n - b * 784;   // rr = y*28+x
                int a  = grp + (quad >> 1);
                p[(b * 32 + a) * 784 + rr] = sv * 0.125f;
            }
        }
    }
}

// ---------------- Kernel 4: FC ----------------
__global__ void k_fc(const float* __restrict__ p, const float* __restrict__ fw,
                     const float* __restrict__ fb, float* __restrict__ out) {
    int b = blockIdx.x, tid = threadIdx.x;
    const float4* p4 = (const float4*)(p + (size_t)b * 25088);
    const float4* w4 = (const float4*)fw;
    float acc[10] = {};
    for (int i = tid; i < 6272; i += 256) {
        float4 v = p4[i];
#pragma unroll
        for (int c = 0; c < 10; ++c) {
            float4 u = w4[c * 6272 + i];
            acc[c] += v.x * u.x + v.y * u.y + v.z * u.z + v.w * u.w;
        }
    }
    __shared__ float red[10][4];
    int lane = tid & 63, wv = tid >> 6;
#pragma unroll
    for (int c = 0; c < 10; ++c) {
        float s = acc[c];
#pragma unroll
        for (int o = 32; o > 0; o >>= 1) s += __shfl_down(s, o, 64);
        if (lane == 0) red[c][wv] = s;
    }
    __syncthreads();
    if (tid < 10)
        out[b * 10 + tid] = red[tid][0] + red[tid][1] + red[tid][2] + red[tid][3] + fb[tid];
}

// ---------------- launch ----------------
extern "C" void kernel_launch(void* const* d_in, const int* in_sizes, int n_in,
                              void* d_out, int out_size, void* d_ws, size_t ws_size,
                              hipStream_t stream) {
    const float* x  = (const float*)d_in[0];
    const float* bw = (const float*)d_in[1];
    const float* w2 = (const float*)d_in[2];
    const float* fw = (const float*)d_in[3];
    const float* fb = (const float*)d_in[4];
    float* out = (float*)d_out;
    char* ws = (char*)d_ws;

    __hip_bfloat16* Amat = (__hip_bfloat16*)(ws + 4608);
    __hip_bfloat16* hl   = (__hip_bfloat16*)(ws + 594432);
    float*          p    = (float*)(ws + 118563328);

    k_build_a<<<1152,   256, 0, stream>>>(w2, Amat);
    k_conv1  <<<7200,   256, 0, stream>>>(x, bw, hl);
    k_conv2  <<<6272,   256, 0, stream>>>(Amat, hl, p);
    k_fc     <<<512,    256, 0, stream>>>(p, fw, fb, out);
}